// Round 9
// baseline (2079.057 us; speedup 1.0000x reference)
//
#include <hip/hip_runtime.h>
#include <math.h>

#define B_  8
#define T_  400
#define F_  256
#define D_  64
#define K_  16
#define N_  (T_*F_)        // 102400
#define TILE 256
#define NBLK (N_/TILE)     // 400
#define CHUNK 64
#define PSLOT 2064         // floats per partial slot: 1024 sx + 1024 sx2 + 16 cs
#define SG 8               // slot groups in reducek
#define SPG (NBLK/SG)      // 50

// ---------------- workspace layout (floats) ----------------
// 16512  pinv    8192   [b][c][k][j], c=d/4, j=d%4
// 24704  pw      8192
// 32896  pc0     128
// 33024  cs      128    \
// 33152  sx      8192    > contiguous, zeroed per iteration (sx2 = sx+8192)
// 41344  sx2     8192   /
// 49536  part    B_*NBLK*PSLOT = 6,604,800  (~26.4 MB)

// init: derived params directly from means_in with var=COV_INIT=1, pi=1/16.
__global__ void initk(const float* __restrict__ means_in,
                      float* __restrict__ pinv, float* __restrict__ pw,
                      float* __restrict__ pc0) {
    int bk = blockIdx.x;          // 0..127
    int b  = bk >> 4;
    int k  = bk & 15;
    int d  = threadIdx.x;         // 0..63
    float m    = means_in[bk * D_ + d];
    const float inv0 = 1.0f / (1.0f + 1e-6f);
    int tck = ((b*16 + (d >> 2))*16 + k)*4 + (d & 3);   // [b][c][k][j]
    pinv[tck] = inv0;
    pw[tck]   = m * inv0;
    float r1 = logf(6.283185307179586f);   // log(2*pi*1.0)
    float r2 = m * m * inv0;
    #pragma unroll
    for (int off = 32; off > 0; off >>= 1) {
        r1 += __shfl_xor(r1, off);
        r2 += __shfl_xor(r2, off);
    }
    if (d == 0) pc0[bk] = logf(1.0f / K_) - 0.5f * (r1 + r2);
}

// fused M-step + param prep: cs/sx/sx2 -> pinv/pw/pc0. one wave per (b,k).
__global__ void mpk(const float* __restrict__ cs, const float* __restrict__ sx,
                    const float* __restrict__ sx2,
                    float* __restrict__ pinv, float* __restrict__ pw,
                    float* __restrict__ pc0) {
    int bk = blockIdx.x;          // 0..127
    int b  = bk >> 4;
    int k  = bk & 15;
    int d  = threadIdx.x;         // 0..63
    float csv = cs[bk];
    float sum = 0.f;
    #pragma unroll
    for (int j = 0; j < 16; ++j) sum += cs[b*K_ + j];
    int idx = bk * D_ + d;
    float sxv = sx[idx], sx2v = sx2[idx];
    float mean = sxv / (csv + 1e-7f);
    float var  = fmaf(mean*mean, csv, fmaf(-2.0f*mean, sxv, sx2v)) + 1e-6f;
    float inv  = 1.0f / (var + 1e-6f);
    int tck = ((b*16 + (d >> 2))*16 + k)*4 + (d & 3);   // [b][c][k][j]
    pinv[tck] = inv;
    pw[tck]   = mean * inv;
    float r1 = logf(6.283185307179586f * var);
    float r2 = mean * mean * inv;
    #pragma unroll
    for (int off = 32; off > 0; off >>= 1) {
        r1 += __shfl_xor(r1, off);
        r2 += __shfl_xor(r2, off);
    }
    if (d == 0) pc0[bk] = logf(csv / sum) - 0.5f * (r1 + r2);
}

// fused E-step. Tile = 256 points, 4 chunks of 64 (28 KB LDS -> 5 blocks/CU).
// Phase A: 4 lanes/point (dim-quarters of 16 dims), x prefetched to regs,
// staged to LDS (float4, xor-swizzled col), params from LDS (4-addr bcast),
// 2-step shuffle reduce, redundant softmax, post -> LDS k-quads (static arms).
// Phase B (round-5 pattern, best measured): lane=(ps,g), wave=k-quad; both
// operands from LDS; per-block partial stores (no atomics).
__global__ __launch_bounds__(256, 5) void estepk(
        const float* __restrict__ xg,
        const float* __restrict__ pinv, const float* __restrict__ pw,
        const float* __restrict__ pc0,
        float* __restrict__ cs, float* __restrict__ sx, float* __restrict__ sx2,
        float* __restrict__ part) {
    __shared__ float4 xl4[16][CHUNK];   // 16 KB; row c: dims 4c..4c+3, col = p ^ (c&7)
    __shared__ float4 post4[4][CHUNK];  // 4 KB;  post4[q][p] = post[4q..4q+3][p]
    __shared__ float4 ivl[256];         // 4 KB;  pinv[b] in [c][k] float4 layout
    __shared__ float4 wvl[256];         // 4 KB;  pw[b]

    const int t  = threadIdx.x;
    const int b  = blockIdx.y;
    const int n0 = blockIdx.x * TILE;
    const int l  = t & 63;
    const int w  = t >> 6;            // wave 0..3

    ivl[t] = ((const float4*)pinv)[b*256 + t];
    wvl[t] = ((const float4*)pw  )[b*256 + t];

    float c0r[16];
    #pragma unroll
    for (int k = 0; k < 16; ++k) c0r[k] = pc0[b*K_ + k];    // uniform

    // phase-A mapping: 4 lanes per point, dim-quarters
    const int pl = w*16 + (l >> 2);   // point within chunk 0..63
    const int q  = l & 3;             // dim quarter: c-groups 4q..4q+3

    // prefetch chunk 0 (wave = 16 points x 256 B contiguous, coalesced)
    const float4* px = (const float4*)xg + ((size_t)b*N_ + n0 + pl) * 16 + 4*q;
    float4 xr[4];
    #pragma unroll
    for (int c = 0; c < 4; ++c) xr[c] = px[c];

    // phase-B mapping + persistent accumulators (round-5 pattern)
    const int g  = l & 15;            // d-group: dims 4g..4g+3
    const int ps = l >> 4;            // point phase 0..3
    float sa[4][4], s2a[4][4], ca[4];
    #pragma unroll
    for (int i = 0; i < 4; ++i) {
        ca[i] = 0.f;
        #pragma unroll
        for (int j = 0; j < 4; ++j) { sa[i][j] = 0.f; s2a[i][j] = 0.f; }
    }

    __syncthreads();                  // params staged

    #pragma unroll 1
    for (int cc = 0; cc < 4; ++cc) {
        // ---- phase A ----
        float t1[16], t2[16];
        #pragma unroll
        for (int k = 0; k < 16; ++k) { t1[k] = 0.f; t2[k] = 0.f; }

        #pragma unroll
        for (int c = 0; c < 4; ++c) {
            float4 xv = xr[c];
            const int cg = 4*q + c;              // global d-group 0..15
            xl4[cg][pl ^ (cg & 7)] = xv;         // swizzled stage
            float4 qv;
            qv.x = xv.x*xv.x; qv.y = xv.y*xv.y; qv.z = xv.z*xv.z; qv.w = xv.w*xv.w;
            const float4* ivc = &ivl[cg*16];
            const float4* wvc = &wvl[cg*16];
            #pragma unroll
            for (int k = 0; k < 16; ++k) {
                float4 iv = ivc[k];              // 4 addrs/wave broadcast
                float4 wv = wvc[k];
                t2[k] = fmaf(qv.x, iv.x, fmaf(qv.y, iv.y, fmaf(qv.z, iv.z, fmaf(qv.w, iv.w, t2[k]))));
                t1[k] = fmaf(xv.x, wv.x, fmaf(xv.y, wv.y, fmaf(xv.z, wv.z, fmaf(xv.w, wv.w, t1[k]))));
            }
        }

        // reduce across the 4 dim-quarters (lanes 4p..4p+3)
        #pragma unroll
        for (int k = 0; k < 16; ++k) {
            t1[k] += __shfl_xor(t1[k], 1);
            t2[k] += __shfl_xor(t2[k], 1);
            t1[k] += __shfl_xor(t1[k], 2);
            t2[k] += __shfl_xor(t2[k], 2);
        }

        // softmax over K=16 (redundant in the 4-lane group); STATIC indices
        float po[16]; float mx = -1e30f;
        #pragma unroll
        for (int k = 0; k < 16; ++k) { po[k] = c0r[k] + t1[k] - 0.5f*t2[k]; mx = fmaxf(mx, po[k]); }
        float s = 0.f;
        #pragma unroll
        for (int k = 0; k < 16; ++k) { po[k] = __expf(po[k] - mx); s += po[k]; }
        float is = 1.0f / s;
        if      (q == 0) post4[0][pl] = make_float4(po[0]*is,  po[1]*is,  po[2]*is,  po[3]*is);
        else if (q == 1) post4[1][pl] = make_float4(po[4]*is,  po[5]*is,  po[6]*is,  po[7]*is);
        else if (q == 2) post4[2][pl] = make_float4(po[8]*is,  po[9]*is,  po[10]*is, po[11]*is);
        else             post4[3][pl] = make_float4(po[12]*is, po[13]*is, po[14]*is, po[15]*is);

        // T14: issue next-chunk global loads; they fly under barrier + phase B
        if (cc < 3) {
            px += CHUNK * 16;
            #pragma unroll
            for (int c = 0; c < 4; ++c) xr[c] = px[c];
        }
        __syncthreads();                 // xl4/post4 ready

        // ---- phase B: all LDS (round-5 pattern) ----
        #pragma unroll 4
        for (int n = 0; n < CHUNK; n += 4) {
            const int p = n + ps;
            float4 xv = xl4[g][p ^ (g & 7)];
            float4 pv = post4[w][p];      // wave-uniform broadcast
            float xf[4] = {xv.x, xv.y, xv.z, xv.w};
            float pf[4] = {pv.x, pv.y, pv.z, pv.w};
            float qf[4];
            #pragma unroll
            for (int j = 0; j < 4; ++j) qf[j] = xf[j]*xf[j];
            #pragma unroll
            for (int i = 0; i < 4; ++i) {
                ca[i] += pf[i];
                #pragma unroll
                for (int j = 0; j < 4; ++j) {
                    sa[i][j]  = fmaf(pf[i], xf[j], sa[i][j]);
                    s2a[i][j] = fmaf(pf[i], qf[j], s2a[i][j]);
                }
            }
        }
        if (cc < 3) __syncthreads();     // before next chunk overwrites LDS
    }

    // reduce across the 4 point-phases (xor 16, then xor 32)
    #pragma unroll
    for (int m = 16; m <= 32; m <<= 1) {
        #pragma unroll
        for (int i = 0; i < 4; ++i) {
            ca[i] += __shfl_xor(ca[i], m);
            #pragma unroll
            for (int j = 0; j < 4; ++j) {
                sa[i][j]  += __shfl_xor(sa[i][j],  m);
                s2a[i][j] += __shfl_xor(s2a[i][j], m);
            }
        }
    }

    const int kb = w * 4;
    if (part) {
        // per-block partial slot, coalesced float4 stores, no atomics
        float* pp = part + ((size_t)(b*NBLK + blockIdx.x)) * PSLOT;
        if (l < 16) {
            #pragma unroll
            for (int i = 0; i < 4; ++i) {
                float4 v1 = make_float4(sa[i][0],  sa[i][1],  sa[i][2],  sa[i][3]);
                float4 v2 = make_float4(s2a[i][0], s2a[i][1], s2a[i][2], s2a[i][3]);
                *(float4*)&pp[(kb + i)*64 + 4*l]        = v1;
                *(float4*)&pp[1024 + (kb + i)*64 + 4*l] = v2;
            }
            if (l == 0) {
                #pragma unroll
                for (int i = 0; i < 4; ++i) pp[2048 + kb + i] = ca[i];
            }
        }
    } else {
        if (l < 16) {
            #pragma unroll
            for (int i = 0; i < 4; ++i) {
                #pragma unroll
                for (int j = 0; j < 4; ++j) {
                    atomicAdd(&sx [(size_t)(b*K_ + kb + i)*D_ + 4*l + j], sa[i][j]);
                    atomicAdd(&sx2[(size_t)(b*K_ + kb + i)*D_ + 4*l + j], s2a[i][j]);
                }
            }
            if (l == 0) {
                #pragma unroll
                for (int i = 0; i < 4; ++i) atomicAdd(&cs[b*K_ + kb + i], ca[i]);
            }
        }
    }
}

// fold NBLK partial slots into cs/sx/sx2. grid (65, SG).
__global__ __launch_bounds__(256) void reducek(const float* __restrict__ part,
                                               float* __restrict__ cs,
                                               float* __restrict__ sx) {
    const int idx = blockIdx.x * 256 + threadIdx.x;
    const int s0  = blockIdx.y * SPG;
    if (idx < B_*2048) {
        const int b = idx >> 11, off = idx & 2047;
        const float* pp = part + ((size_t)(b*NBLK + s0)) * PSLOT + off;
        float sum = 0.f;
        #pragma unroll 10
        for (int s = 0; s < SPG; ++s) sum += pp[(size_t)s * PSLOT];
        float* dst = (off < 1024) ? (sx + b*1024 + off)
                                  : (sx + 8192 + b*1024 + (off - 1024));   // sx2
        atomicAdd(dst, sum);
    } else if (idx < B_*2048 + B_*K_) {
        const int c = idx - B_*2048;
        const int b = c >> 4, k = c & 15;
        const float* pp = part + ((size_t)(b*NBLK + s0)) * PSLOT + 2048 + k;
        float sum = 0.f;
        #pragma unroll 10
        for (int s = 0; s < SPG; ++s) sum += pp[(size_t)s * PSLOT];
        atomicAdd(&cs[b*16 + k], sum);
    }
}

// final lik -> sigmoid(scale*lik + bias) -> out[b][n][k]; one point per thread
__global__ __launch_bounds__(256, 6) void finalk(
        const float* __restrict__ xg,
        const float* __restrict__ pinv, const float* __restrict__ pw,
        const float* __restrict__ pc0,
        const float* __restrict__ scale, const float* __restrict__ bias,
        float* __restrict__ out) {
    const int t  = threadIdx.x;
    const int b  = blockIdx.y;
    const int n0 = blockIdx.x * TILE;

    const float4* iv4 = (const float4*)(pinv + (size_t)(b*K_*D_));
    const float4* wv4 = (const float4*)(pw   + (size_t)(b*K_*D_));

    float c0r[16];
    #pragma unroll
    for (int k = 0; k < 16; ++k) c0r[k] = pc0[b*K_ + k];

    const float4* px = (const float4*)(xg + ((size_t)b*N_ + n0 + t) * D_);

    float t1[16], t2[16];
    #pragma unroll
    for (int k = 0; k < 16; ++k) { t1[k] = 0.f; t2[k] = 0.f; }

    #pragma unroll 4
    for (int c = 0; c < D_/4; ++c) {
        float4 xv = px[c];
        float4 qv;
        qv.x = xv.x*xv.x; qv.y = xv.y*xv.y; qv.z = xv.z*xv.z; qv.w = xv.w*xv.w;
        const float4* ivc = iv4 + c*16;
        const float4* wvc = wv4 + c*16;
        #pragma unroll
        for (int k = 0; k < 16; ++k) {
            float4 iv = ivc[k];
            float4 wv = wvc[k];
            t2[k] = fmaf(qv.x, iv.x, fmaf(qv.y, iv.y, fmaf(qv.z, iv.z, fmaf(qv.w, iv.w, t2[k]))));
            t1[k] = fmaf(xv.x, wv.x, fmaf(xv.y, wv.y, fmaf(xv.z, wv.z, fmaf(xv.w, wv.w, t1[k]))));
        }
    }

    const float sc = scale[0], bi = bias[0];
    float4* op = (float4*)(out + ((size_t)b*N_ + n0 + t) * (size_t)K_);
    #pragma unroll
    for (int q = 0; q < 4; ++q) {
        float4 o;
        float z0 = (c0r[4*q+0] + t1[4*q+0] - 0.5f*t2[4*q+0]) * sc + bi;
        float z1 = (c0r[4*q+1] + t1[4*q+1] - 0.5f*t2[4*q+1]) * sc + bi;
        float z2 = (c0r[4*q+2] + t1[4*q+2] - 0.5f*t2[4*q+2]) * sc + bi;
        float z3 = (c0r[4*q+3] + t1[4*q+3] - 0.5f*t2[4*q+3]) * sc + bi;
        o.x = 1.0f / (1.0f + __expf(-z0));
        o.y = 1.0f / (1.0f + __expf(-z1));
        o.z = 1.0f / (1.0f + __expf(-z2));
        o.w = 1.0f / (1.0f + __expf(-z3));
        op[q] = o;
    }
}

extern "C" void kernel_launch(void* const* d_in, const int* in_sizes, int n_in,
                              void* d_out, int out_size, void* d_ws, size_t ws_size,
                              hipStream_t stream) {
    const float* xg       = (const float*)d_in[0];
    const float* means_in = (const float*)d_in[1];
    const float* scale    = (const float*)d_in[2];
    const float* bias     = (const float*)d_in[3];
    float* out = (float*)d_out;

    float* ws      = (float*)d_ws;
    float* pinv    = ws + 16512;
    float* pw      = ws + 24704;
    float* pc0     = ws + 32896;
    float* cs      = ws + 33024;
    float* sx      = ws + 33152;
    // sx2 = sx + 8192 (contiguous; reducek relies on this)
    float* sx2     = ws + 41344;
    float* part    = ws + 49536;

    const size_t need_floats = (size_t)49536 + (size_t)B_ * NBLK * PSLOT;  // ~26.6 MB
    if (ws_size < need_floats * sizeof(float)) part = nullptr;

    initk<<<dim3(B_*K_), dim3(64), 0, stream>>>(means_in, pinv, pw, pc0);

    for (int it = 0; it < 5; ++it) {
        hipMemsetAsync(cs, 0, (size_t)(128 + 8192 + 8192) * sizeof(float), stream);
        estepk<<<dim3(NBLK, B_), dim3(256), 0, stream>>>(xg, pinv, pw, pc0, cs, sx, sx2, part);
        if (part)
            reducek<<<dim3(65, SG), dim3(256), 0, stream>>>(part, cs, sx);
        mpk<<<dim3(B_*K_), dim3(64), 0, stream>>>(cs, sx, sx2, pinv, pw, pc0);
    }
    finalk<<<dim3(NBLK, B_), dim3(256), 0, stream>>>(xg, pinv, pw, pc0, scale, bias, out);
}

// Round 10
// 1020.976 us; speedup vs baseline: 2.0363x; 2.0363x over previous
//
#include <hip/hip_runtime.h>
#include <math.h>

#define B_  8
#define T_  400
#define F_  256
#define D_  64
#define K_  16
#define N_  (T_*F_)        // 102400
#define TILE 256
#define NBLK (N_/TILE)     // 400
#define PSLOT 2064         // floats per partial slot: 1024 sx + 1024 sx2 + 16 cs
#define SG 8               // slot groups in reducek
#define SPG (NBLK/SG)      // 50

// ---------------- workspace layout (floats) ----------------
// 16512  pinv    8192   [b][c][k][j], c=d/4, j=d%4
// 24704  pw      8192
// 32896  pc0     128
// 33024  cs      128    \
// 33152  sx      8192    > contiguous, zeroed per iteration (sx2 = sx+8192)
// 41344  sx2     8192   /
// 49536  part    B_*NBLK*PSLOT = 6,604,800  (~26.4 MB)

// init: derived params directly from means_in with var=COV_INIT=1, pi=1/16.
__global__ void initk(const float* __restrict__ means_in,
                      float* __restrict__ pinv, float* __restrict__ pw,
                      float* __restrict__ pc0) {
    int bk = blockIdx.x;          // 0..127
    int b  = bk >> 4;
    int k  = bk & 15;
    int d  = threadIdx.x;         // 0..63
    float m    = means_in[bk * D_ + d];
    const float inv0 = 1.0f / (1.0f + 1e-6f);
    int tck = ((b*16 + (d >> 2))*16 + k)*4 + (d & 3);   // [b][c][k][j]
    pinv[tck] = inv0;
    pw[tck]   = m * inv0;
    float r1 = logf(6.283185307179586f);   // log(2*pi*1.0)
    float r2 = m * m * inv0;
    #pragma unroll
    for (int off = 32; off > 0; off >>= 1) {
        r1 += __shfl_xor(r1, off);
        r2 += __shfl_xor(r2, off);
    }
    if (d == 0) pc0[bk] = logf(1.0f / K_) - 0.5f * (r1 + r2);
}

// fused M-step + param prep: cs/sx/sx2 -> pinv/pw/pc0. one wave per (b,k).
__global__ void mpk(const float* __restrict__ cs, const float* __restrict__ sx,
                    const float* __restrict__ sx2,
                    float* __restrict__ pinv, float* __restrict__ pw,
                    float* __restrict__ pc0) {
    int bk = blockIdx.x;          // 0..127
    int b  = bk >> 4;
    int k  = bk & 15;
    int d  = threadIdx.x;         // 0..63
    float csv = cs[bk];
    float sum = 0.f;
    #pragma unroll
    for (int j = 0; j < 16; ++j) sum += cs[b*K_ + j];
    int idx = bk * D_ + d;
    float sxv = sx[idx], sx2v = sx2[idx];
    float mean = sxv / (csv + 1e-7f);
    float var  = fmaf(mean*mean, csv, fmaf(-2.0f*mean, sxv, sx2v)) + 1e-6f;
    float inv  = 1.0f / (var + 1e-6f);
    int tck = ((b*16 + (d >> 2))*16 + k)*4 + (d & 3);   // [b][c][k][j]
    pinv[tck] = inv;
    pw[tck]   = mean * inv;
    float r1 = logf(6.283185307179586f * var);
    float r2 = mean * mean * inv;
    #pragma unroll
    for (int off = 32; off > 0; off >>= 1) {
        r1 += __shfl_xor(r1, off);
        r2 += __shfl_xor(r2, off);
    }
    if (d == 0) pc0[bk] = logf(csv / sum) - 0.5f * (r1 + r2);
}

// fused E-step, round-3 structure + LDS params + conflict-free post stores.
// Phase A: ONE point per thread, x via float4 global loads (L3-resident),
// params from LDS (wave-uniform broadcast ds_read_b128), per-thread softmax,
// post -> post4[q][t] (canonical 16B/lane stores, conflict-free).
// Phase B: round-3 pattern (lane=(ps,g), wave=k-quad), x re-read from global
// (L3 absorbs: measured round 3/5 identical time), post4 broadcast from LDS.
// NOTE: VGPR granularity is {64,128,256} — bound (256,6) targets the <=64
// step; round-9's (256,5) forced <=64 with ~100 live regs -> 647 MB spill.
__global__ __launch_bounds__(256, 6) void estepk(
        const float* __restrict__ xg,
        const float* __restrict__ pinv, const float* __restrict__ pw,
        const float* __restrict__ pc0,
        float* __restrict__ cs, float* __restrict__ sx, float* __restrict__ sx2,
        float* __restrict__ part) {
    __shared__ float4 post4[4][TILE];   // 16 KB; post4[q][p] = post[4q..4q+3][p]
    __shared__ float4 ivl[256];         // 4 KB;  pinv[b] in [c][k] float4 layout
    __shared__ float4 wvl[256];         // 4 KB;  pw[b]

    const int t  = threadIdx.x;
    const int b  = blockIdx.y;
    const int n0 = blockIdx.x * TILE;
    const int l  = t & 63;
    const int w  = t >> 6;            // wave 0..3

    ivl[t] = ((const float4*)pinv)[b*256 + t];
    wvl[t] = ((const float4*)pw  )[b*256 + t];

    float c0r[16];
    #pragma unroll
    for (int k = 0; k < 16; ++k) c0r[k] = pc0[b*K_ + k];    // uniform -> s_load

    __syncthreads();                  // params staged

    // ---- phase A: one point per thread ----
    const float4* px = (const float4*)(xg + ((size_t)b*N_ + n0 + t) * D_);

    float t1[16], t2[16];
    #pragma unroll
    for (int k = 0; k < 16; ++k) { t1[k] = 0.f; t2[k] = 0.f; }

    #pragma unroll 4
    for (int c = 0; c < D_/4; ++c) {
        float4 xv = px[c];
        float4 qv;
        qv.x = xv.x*xv.x; qv.y = xv.y*xv.y; qv.z = xv.z*xv.z; qv.w = xv.w*xv.w;
        const float4* ivc = &ivl[c*16];
        const float4* wvc = &wvl[c*16];
        #pragma unroll
        for (int k = 0; k < 16; ++k) {
            float4 iv = ivc[k];           // wave-uniform -> LDS broadcast
            float4 wv = wvc[k];
            t2[k] = fmaf(qv.x, iv.x, fmaf(qv.y, iv.y, fmaf(qv.z, iv.z, fmaf(qv.w, iv.w, t2[k]))));
            t1[k] = fmaf(xv.x, wv.x, fmaf(xv.y, wv.y, fmaf(xv.z, wv.z, fmaf(xv.w, wv.w, t1[k]))));
        }
    }

    // softmax over K=16 in-thread; post -> post4 (static indices, 16B/lane)
    {
        float po[16]; float mx = -1e30f;
        #pragma unroll
        for (int k = 0; k < 16; ++k) { po[k] = c0r[k] + t1[k] - 0.5f*t2[k]; mx = fmaxf(mx, po[k]); }
        float s = 0.f;
        #pragma unroll
        for (int k = 0; k < 16; ++k) { po[k] = __expf(po[k] - mx); s += po[k]; }
        float is = 1.0f / s;
        post4[0][t] = make_float4(po[0]*is,  po[1]*is,  po[2]*is,  po[3]*is);
        post4[1][t] = make_float4(po[4]*is,  po[5]*is,  po[6]*is,  po[7]*is);
        post4[2][t] = make_float4(po[8]*is,  po[9]*is,  po[10]*is, po[11]*is);
        post4[3][t] = make_float4(po[12]*is, po[13]*is, po[14]*is, po[15]*is);
    }
    __syncthreads();

    // ---- phase B: wave w -> k in [4w,4w+4); lane = (ps<<4)|g ----
    const int g  = l & 15;            // d-group: dims 4g..4g+3
    const int ps = l >> 4;            // point phase 0..3
    const int kb = w * 4;

    float sa[4][4], s2a[4][4], ca[4];
    #pragma unroll
    for (int i = 0; i < 4; ++i) {
        ca[i] = 0.f;
        #pragma unroll
        for (int j = 0; j < 4; ++j) { sa[i][j] = 0.f; s2a[i][j] = 0.f; }
    }

    const float4* xq = (const float4*)(xg + ((size_t)b*N_ + n0) * D_);

    #pragma unroll 4
    for (int n = 0; n < TILE; n += 4) {
        const int p = n + ps;
        float4 xv = xq[p*16 + g];
        float4 pv = post4[w][p];      // 4-address broadcast
        float xf[4] = {xv.x, xv.y, xv.z, xv.w};
        float pf[4] = {pv.x, pv.y, pv.z, pv.w};
        float qf[4];
        #pragma unroll
        for (int j = 0; j < 4; ++j) qf[j] = xf[j]*xf[j];
        #pragma unroll
        for (int i = 0; i < 4; ++i) {
            ca[i] += pf[i];
            #pragma unroll
            for (int j = 0; j < 4; ++j) {
                sa[i][j]  = fmaf(pf[i], xf[j], sa[i][j]);
                s2a[i][j] = fmaf(pf[i], qf[j], s2a[i][j]);
            }
        }
    }

    // reduce across the 4 point-phases (xor 16, then xor 32)
    #pragma unroll
    for (int m = 16; m <= 32; m <<= 1) {
        #pragma unroll
        for (int i = 0; i < 4; ++i) {
            ca[i] += __shfl_xor(ca[i], m);
            #pragma unroll
            for (int j = 0; j < 4; ++j) {
                sa[i][j]  += __shfl_xor(sa[i][j],  m);
                s2a[i][j] += __shfl_xor(s2a[i][j], m);
            }
        }
    }

    if (part) {
        // per-block partial slot, coalesced float4 stores, no atomics
        float* pp = part + ((size_t)(b*NBLK + blockIdx.x)) * PSLOT;
        if (l < 16) {
            #pragma unroll
            for (int i = 0; i < 4; ++i) {
                float4 v1 = make_float4(sa[i][0],  sa[i][1],  sa[i][2],  sa[i][3]);
                float4 v2 = make_float4(s2a[i][0], s2a[i][1], s2a[i][2], s2a[i][3]);
                *(float4*)&pp[(kb + i)*64 + 4*l]        = v1;
                *(float4*)&pp[1024 + (kb + i)*64 + 4*l] = v2;
            }
            if (l == 0) {
                #pragma unroll
                for (int i = 0; i < 4; ++i) pp[2048 + kb + i] = ca[i];
            }
        }
    } else {
        if (l < 16) {
            #pragma unroll
            for (int i = 0; i < 4; ++i) {
                #pragma unroll
                for (int j = 0; j < 4; ++j) {
                    atomicAdd(&sx [(size_t)(b*K_ + kb + i)*D_ + 4*l + j], sa[i][j]);
                    atomicAdd(&sx2[(size_t)(b*K_ + kb + i)*D_ + 4*l + j], s2a[i][j]);
                }
            }
            if (l == 0) {
                #pragma unroll
                for (int i = 0; i < 4; ++i) atomicAdd(&cs[b*K_ + kb + i], ca[i]);
            }
        }
    }
}

// fold NBLK partial slots into cs/sx/sx2. grid (65, SG).
__global__ __launch_bounds__(256) void reducek(const float* __restrict__ part,
                                               float* __restrict__ cs,
                                               float* __restrict__ sx) {
    const int idx = blockIdx.x * 256 + threadIdx.x;
    const int s0  = blockIdx.y * SPG;
    if (idx < B_*2048) {
        const int b = idx >> 11, off = idx & 2047;
        const float* pp = part + ((size_t)(b*NBLK + s0)) * PSLOT + off;
        float sum = 0.f;
        #pragma unroll 10
        for (int s = 0; s < SPG; ++s) sum += pp[(size_t)s * PSLOT];
        float* dst = (off < 1024) ? (sx + b*1024 + off)
                                  : (sx + 8192 + b*1024 + (off - 1024));   // sx2
        atomicAdd(dst, sum);
    } else if (idx < B_*2048 + B_*K_) {
        const int c = idx - B_*2048;
        const int b = c >> 4, k = c & 15;
        const float* pp = part + ((size_t)(b*NBLK + s0)) * PSLOT + 2048 + k;
        float sum = 0.f;
        #pragma unroll 10
        for (int s = 0; s < SPG; ++s) sum += pp[(size_t)s * PSLOT];
        atomicAdd(&cs[b*16 + k], sum);
    }
}

// final lik -> sigmoid(scale*lik + bias) -> out[b][n][k]; one point per thread.
// Same LDS-param treatment as estepk (8 KB LDS only).
__global__ __launch_bounds__(256, 6) void finalk(
        const float* __restrict__ xg,
        const float* __restrict__ pinv, const float* __restrict__ pw,
        const float* __restrict__ pc0,
        const float* __restrict__ scale, const float* __restrict__ bias,
        float* __restrict__ out) {
    __shared__ float4 ivl[256];         // 4 KB
    __shared__ float4 wvl[256];         // 4 KB

    const int t  = threadIdx.x;
    const int b  = blockIdx.y;
    const int n0 = blockIdx.x * TILE;

    ivl[t] = ((const float4*)pinv)[b*256 + t];
    wvl[t] = ((const float4*)pw  )[b*256 + t];

    float c0r[16];
    #pragma unroll
    for (int k = 0; k < 16; ++k) c0r[k] = pc0[b*K_ + k];

    __syncthreads();

    const float4* px = (const float4*)(xg + ((size_t)b*N_ + n0 + t) * D_);

    float t1[16], t2[16];
    #pragma unroll
    for (int k = 0; k < 16; ++k) { t1[k] = 0.f; t2[k] = 0.f; }

    #pragma unroll 4
    for (int c = 0; c < D_/4; ++c) {
        float4 xv = px[c];
        float4 qv;
        qv.x = xv.x*xv.x; qv.y = xv.y*xv.y; qv.z = xv.z*xv.z; qv.w = xv.w*xv.w;
        const float4* ivc = &ivl[c*16];
        const float4* wvc = &wvl[c*16];
        #pragma unroll
        for (int k = 0; k < 16; ++k) {
            float4 iv = ivc[k];
            float4 wv = wvc[k];
            t2[k] = fmaf(qv.x, iv.x, fmaf(qv.y, iv.y, fmaf(qv.z, iv.z, fmaf(qv.w, iv.w, t2[k]))));
            t1[k] = fmaf(xv.x, wv.x, fmaf(xv.y, wv.y, fmaf(xv.z, wv.z, fmaf(xv.w, wv.w, t1[k]))));
        }
    }

    const float sc = scale[0], bi = bias[0];
    float4* op = (float4*)(out + ((size_t)b*N_ + n0 + t) * (size_t)K_);
    #pragma unroll
    for (int q = 0; q < 4; ++q) {
        float4 o;
        float z0 = (c0r[4*q+0] + t1[4*q+0] - 0.5f*t2[4*q+0]) * sc + bi;
        float z1 = (c0r[4*q+1] + t1[4*q+1] - 0.5f*t2[4*q+1]) * sc + bi;
        float z2 = (c0r[4*q+2] + t1[4*q+2] - 0.5f*t2[4*q+2]) * sc + bi;
        float z3 = (c0r[4*q+3] + t1[4*q+3] - 0.5f*t2[4*q+3]) * sc + bi;
        o.x = 1.0f / (1.0f + __expf(-z0));
        o.y = 1.0f / (1.0f + __expf(-z1));
        o.z = 1.0f / (1.0f + __expf(-z2));
        o.w = 1.0f / (1.0f + __expf(-z3));
        op[q] = o;
    }
}

extern "C" void kernel_launch(void* const* d_in, const int* in_sizes, int n_in,
                              void* d_out, int out_size, void* d_ws, size_t ws_size,
                              hipStream_t stream) {
    const float* xg       = (const float*)d_in[0];
    const float* means_in = (const float*)d_in[1];
    const float* scale    = (const float*)d_in[2];
    const float* bias     = (const float*)d_in[3];
    float* out = (float*)d_out;

    float* ws      = (float*)d_ws;
    float* pinv    = ws + 16512;
    float* pw      = ws + 24704;
    float* pc0     = ws + 32896;
    float* cs      = ws + 33024;
    float* sx      = ws + 33152;
    // sx2 = sx + 8192 (contiguous; reducek relies on this)
    float* sx2     = ws + 41344;
    float* part    = ws + 49536;

    const size_t need_floats = (size_t)49536 + (size_t)B_ * NBLK * PSLOT;  // ~26.6 MB
    if (ws_size < need_floats * sizeof(float)) part = nullptr;

    initk<<<dim3(B_*K_), dim3(64), 0, stream>>>(means_in, pinv, pw, pc0);

    for (int it = 0; it < 5; ++it) {
        hipMemsetAsync(cs, 0, (size_t)(128 + 8192 + 8192) * sizeof(float), stream);
        estepk<<<dim3(NBLK, B_), dim3(256), 0, stream>>>(xg, pinv, pw, pc0, cs, sx, sx2, part);
        if (part)
            reducek<<<dim3(65, SG), dim3(256), 0, stream>>>(part, cs, sx);
        mpk<<<dim3(B_*K_), dim3(64), 0, stream>>>(cs, sx, sx2, pinv, pw, pc0);
    }
    finalk<<<dim3(NBLK, B_), dim3(256), 0, stream>>>(xg, pinv, pw, pc0, scale, bias, out);
}